// Round 14
// baseline (382.452 us; speedup 1.0000x reference)
//
#include <hip/hip_runtime.h>
#include <hip/hip_bf16.h>
#include <math.h>

typedef __bf16 bf16_t;
typedef __bf16 bf16x4_t __attribute__((ext_vector_type(4)));
typedef __bf16 bf16x8_t __attribute__((ext_vector_type(8)));
typedef float  f32x4_t  __attribute__((ext_vector_type(4)));

#define N_TOK 4096
#define D_IN  4096
#define O_OUT 4096
#define NEXP  8
#define NHEAD 3
#define RANK  16
#define KC2   384      // E*H*R
#define PCOLS 256      // padded projection cols (152 used)
#define NKZ   8        // proj split-K factor
#define SCALING_F 2.0f

// ---------------- prep building blocks ----------------

// 64x64 transpose tile fp32 -> bf16; 16B bf16x8 stores; LDS reads 2-way aliased (free).
__device__ __forceinline__ void transpose_tile(const float* __restrict__ src,
                                               bf16_t* __restrict__ dst,
                                               int Rr, int Cc, int r0, int c0,
                                               float (*tile)[65]) {
  int q  = threadIdx.x & 15;
  int r4 = threadIdx.x >> 4;
  #pragma unroll
  for (int g = 0; g < 4; ++g) {
    int r = r4 + g * 16;
    float4 v = *(const float4*)(src + (size_t)(r0 + r) * Cc + c0 + q * 4);
    tile[r][q * 4 + 0] = v.x; tile[r][q * 4 + 1] = v.y;
    tile[r][q * 4 + 2] = v.z; tile[r][q * 4 + 3] = v.w;
  }
  __syncthreads();
  int j  = threadIdx.x & 7;   // out col-chunk (8 src rows)
  int cc = threadIdx.x >> 3;  // out row 0..31 (+32)
  #pragma unroll
  for (int h = 0; h < 2; ++h) {
    int c = cc + h * 32;
    bf16x8_t o;
    #pragma unroll
    for (int i = 0; i < 8; ++i) o[i] = (bf16_t)tile[j * 8 + i][c];
    *(bf16x8_t*)(dst + (size_t)(c0 + c) * Rr + r0 + j * 8) = o;
  }
}

// ---------------- ONE prep kernel: all independent pre-GEMM work ----------------
__global__ __launch_bounds__(256) void prep_kernel(const float* __restrict__ x,
                                                   const float* __restrict__ base_W,
                                                   const float* __restrict__ rw,
                                                   const float* __restrict__ A,
                                                   const float* __restrict__ B,
                                                   const float* __restrict__ Rm,
                                                   bf16_t* __restrict__ xb,
                                                   bf16_t* __restrict__ WbT,
                                                   bf16_t* __restrict__ BbT,
                                                   bf16_t* __restrict__ PabT,
                                                   int* __restrict__ gidx,
                                                   float* __restrict__ gwv) {
  __shared__ float tile[64][65];
  int b = blockIdx.x;
  if (b < 4096) {
    transpose_tile(base_W, WbT, 4096, 4096, (b & 63) * 64, (b >> 6) * 64, tile);
  } else if (b < 5120) {
    int lane = threadIdx.x & 63;
    int wv = threadIdx.x >> 6;
    int n = (b - 4096) * 4 + wv;
    const float4* xv = (const float4*)(x + (size_t)n * D_IN);
    bf16x4_t* xo = (bf16x4_t*)(xb + (size_t)n * D_IN);
    float acc[NEXP] = {0, 0, 0, 0, 0, 0, 0, 0};
    for (int d = lane; d < D_IN / 4; d += 64) {
      float4 xx = xv[d];
      bf16x4_t ob = { (bf16_t)xx.x, (bf16_t)xx.y, (bf16_t)xx.z, (bf16_t)xx.w };
      xo[d] = ob;
      #pragma unroll
      for (int e = 0; e < NEXP; ++e) {
        float4 ww = ((const float4*)(rw + (size_t)e * D_IN))[d];
        acc[e] += xx.x * ww.x + xx.y * ww.y + xx.z * ww.z + xx.w * ww.w;
      }
    }
    #pragma unroll
    for (int e = 0; e < NEXP; ++e) {
      float v = acc[e];
      #pragma unroll
      for (int o = 32; o > 0; o >>= 1) v += __shfl_down(v, o);
      acc[e] = v;
    }
    if (lane == 0) {
      int i0 = 0; float l0 = acc[0];
      #pragma unroll
      for (int e = 1; e < NEXP; ++e) if (acc[e] > l0) { l0 = acc[e]; i0 = e; }
      int i1 = -1; float l1 = -3.4e38f;
      #pragma unroll
      for (int e = 0; e < NEXP; ++e) if (e != i0 && acc[e] > l1) { l1 = acc[e]; i1 = e; }
      float w0 = 1.f / (1.f + expf(l1 - l0));
      gidx[2 * n] = i0; gidx[2 * n + 1] = i1;
      gwv[2 * n] = w0;  gwv[2 * n + 1] = 1.f - w0;
    }
  } else if (b < 5504) {
    int t = b - 5120;
    transpose_tile(B, BbT, KC2, 4096, (t % 6) * 64, (t / 6) * 64, tile);
  } else {
    int c = b - 5504;  // 0..255: output row of PabT
    for (int d = threadIdx.x; d < D_IN; d += 256) {
      float v = 0.f;
      if (c < 128) {
        int e = c >> 4, r = c & 15;
        v = A[((size_t)e * D_IN + d) * RANK + r];
      } else if (c < 152) {
        int qq = c - 128; int e = qq / 3, h = qq - 3 * e;
        v = Rm[((size_t)e * D_IN + d) * NHEAD + h];
      }
      PabT[(size_t)c * D_IN + d] = (bf16_t)v;
    }
  }
}

// ---------------- gating: C2[n, e*48+h*16+r], summing NKZ split-K partials ----------------
__global__ void gating_kernel(const float* __restrict__ projP, const int* __restrict__ gidx,
                              const float* __restrict__ gwv, bf16_t* __restrict__ C2b) {
  int n = blockIdx.x;
  int c = threadIdx.x;  // 0..383
  int e = c / 48;
  int h = (c % 48) / 16;
  int r = c & 15;
  int i0 = gidx[2 * n], i1 = gidx[2 * n + 1];
  float g = (e == i0) ? gwv[2 * n] : (e == i1) ? gwv[2 * n + 1] : 0.f;
  float val = 0.f;
  if (g != 0.f) {
    const float* p0 = projP + (size_t)n * PCOLS;
    const size_t S = (size_t)N_TOK * PCOLS;
    float h0 = 0.f, h1 = 0.f, h2 = 0.f, av = 0.f;
    #pragma unroll
    for (int z = 0; z < NKZ; ++z) {
      const float* pz = p0 + (size_t)z * S;
      h0 += pz[128 + e * 3 + 0];
      h1 += pz[128 + e * 3 + 1];
      h2 += pz[128 + e * 3 + 2];
      av += pz[e * 16 + r];
    }
    float mx = fmaxf(h0, fmaxf(h1, h2));
    float e0 = expf(h0 - mx), e1 = expf(h1 - mx), e2 = expf(h2 - mx);
    float hw = (h == 0 ? e0 : h == 1 ? e1 : e2) / (e0 + e1 + e2);
    val = SCALING_F * g * hw * av;
  }
  C2b[(size_t)n * KC2 + c] = (bf16_t)val;
}

// ---------------- m97-style MFMA K-loop core (used by proj GEMM only) ----------------
__device__ __forceinline__ void run_kloop(f32x4_t (&acc)[4][4], bf16_t* sA, bf16_t* sB,
                                          const bf16_t* __restrict__ Ab, int lda,
                                          const bf16_t* __restrict__ Bb, int ldb, int K) {
  const int tid = threadIdx.x;
  const int lane = tid & 63;
  const int w = tid >> 6;
  const int wm = (w >> 1) * 64;
  const int wn = (w & 1) * 64;
  const int qd = lane >> 4;
  const int ln = lane & 15;
  const int sw = ln & 7;

  size_t offA[4], offB[4];
  int lo[4];
  #pragma unroll
  for (int t = 0; t < 4; ++t) {
    int c = tid + t * 256;
    int m = c >> 3, kc = (c & 7) ^ (m & 7);
    offA[t] = (size_t)m * lda + kc * 8;
    offB[t] = (size_t)m * ldb + kc * 8;
    lo[t] = c * 8;
  }
  int rowA[4], rowB[4];
  #pragma unroll
  for (int i = 0; i < 4; ++i) {
    rowA[i] = (wm + i * 16 + ln) * 64;
    rowB[i] = (wn + i * 16 + ln) * 64;
  }

  for (int k0 = 0; k0 < K; k0 += 64) {
    __syncthreads();
    #pragma unroll
    for (int t = 0; t < 4; ++t)
      __builtin_amdgcn_global_load_lds(
          (const __attribute__((address_space(1))) void*)(Ab + k0 + offA[t]),
          (__attribute__((address_space(3))) void*)(sA + lo[t]), 16, 0, 0);
    #pragma unroll
    for (int t = 0; t < 4; ++t)
      __builtin_amdgcn_global_load_lds(
          (const __attribute__((address_space(1))) void*)(Bb + k0 + offB[t]),
          (__attribute__((address_space(3))) void*)(sB + lo[t]), 16, 0, 0);
    __syncthreads();
    #pragma unroll
    for (int s = 0; s < 2; ++s) {
      bf16x8_t af[4], bfr[4];
      int kx = ((s * 4 + qd) ^ sw) * 8;
      #pragma unroll
      for (int i = 0; i < 4; ++i) af[i]  = *(const bf16x8_t*)(sA + rowA[i] + kx);
      #pragma unroll
      for (int i = 0; i < 4; ++i) bfr[i] = *(const bf16x8_t*)(sB + rowB[i] + kx);
      #pragma unroll
      for (int i = 0; i < 4; ++i)
        #pragma unroll
        for (int j = 0; j < 4; ++j)
          acc[i][j] = __builtin_amdgcn_mfma_f32_16x16x32_bf16(af[i], bfr[j], acc[i][j], 0, 0, 0);
    }
  }
}

// proj split-K GEMM: projP[kz][4096,256] = xb @ PabT^T partial (K slice 512), 2 blocks/CU.
__global__ __launch_bounds__(256) void gemm_proj_kernel(const bf16_t* __restrict__ xb,
                                                        const bf16_t* __restrict__ PabT,
                                                        float* __restrict__ projP) {
  __shared__ bf16_t sA[128 * 64];
  __shared__ bf16_t sB[128 * 64];
  int bm = blockIdx.x, bn = blockIdx.y, kz = blockIdx.z;
  f32x4_t acc[4][4] = {};
  run_kloop(acc, sA, sB,
            xb + (size_t)bm * 128 * D_IN + kz * 512, D_IN,
            PabT + (size_t)bn * 128 * D_IN + kz * 512, D_IN, 512);
  const int lane = threadIdx.x & 63, w = threadIdx.x >> 6;
  const int wm = (w >> 1) * 64, wn = (w & 1) * 64, qd = lane >> 4, ln = lane & 15;
  float* Cb = projP + (size_t)kz * N_TOK * PCOLS + (size_t)bm * 128 * PCOLS + bn * 128;
  #pragma unroll
  for (int i = 0; i < 4; ++i)
    #pragma unroll
    for (int j = 0; j < 4; ++j) {
      int col = wn + j * 16 + ln;
      #pragma unroll
      for (int rg = 0; rg < 4; ++rg) {
        int row = wm + i * 16 + qd * 4 + rg;
        Cb[(size_t)row * PCOLS + col] = acc[i][j][rg];
      }
    }
}

// ---------------- fused big GEMM: 128x256 tile, BK=32, ring-2, 2 BLOCKS/CU ------------
// Round-14: completes R12's diagnosis. R12 (16 waves, ONE block, 42% occupancy) regressed
// because all waves shared the same block-wide barriers. Here: same per-wave work
// (64x64, acc[4][4] = 64 AGPR; R12 compiled to 64V+64A = 128 regs) and same 16 waves/CU,
// but as TWO independent 8-wave blocks (LDS ring-2 = 48 KB/block -> 2 blocks/CU).
// Barriers are block-local: while block A waits at its barrier/read window, block B's
// waves feed the MFMA pipe (m114 cross-block overlap -- the mechanism behind m97's
// multi-block 912 TF, absent in our 1-block/CU R6 kernel).
// Ledger (ring-2): prologue stage tile0 (3 glds). Body t: stage t+1 into slot t&1^1
// (3 glds, 6 outstanding) -> vmcnt(3) drains tile t exactly -> BAR -> 8 swizzled
// ds_read_b128 -> 16 MFMA (consumed pre-end-BAR, so ring-2 overwrite is race-free) ->
// sched_barrier -> end-BAR (slot t&1 re-stageable). Tail: vmcnt(0).
// Swizzle: identical [*][32]-row math as the verified-0-conflict R6 kernel.

__device__ __forceinline__ void stageH(const bf16_t* __restrict__ Ag,
                                       const bf16_t* __restrict__ Bg, int k0,
                                       bf16_t* slot, size_t gA, size_t gB0, size_t gB1,
                                       int tid) {
  __builtin_amdgcn_global_load_lds(
      (const __attribute__((address_space(1))) void*)(Ag + gA + k0),
      (__attribute__((address_space(3))) void*)(slot + tid * 8), 16, 0, 0);
  __builtin_amdgcn_global_load_lds(
      (const __attribute__((address_space(1))) void*)(Bg + gB0 + k0),
      (__attribute__((address_space(3))) void*)(slot + 4096 + tid * 8), 16, 0, 0);
  __builtin_amdgcn_global_load_lds(
      (const __attribute__((address_space(1))) void*)(Bg + gB1 + k0),
      (__attribute__((address_space(3))) void*)(slot + 8192 + tid * 8), 16, 0, 0);
}

template <int N>
__device__ __forceinline__ void vm_wait() {
  if constexpr (N == 3)      asm volatile("s_waitcnt vmcnt(3)" ::: "memory");
  else if constexpr (N == 0) asm volatile("s_waitcnt vmcnt(0)" ::: "memory");
}

// one tile body (slot SC = t&1): optional stage of t+1 into SC^1, wait, barrier,
// 8 frag reads, 16 MFMA, pin, end barrier.
template <int SC, bool STAGE, int VMN>
__device__ __forceinline__ void tbodyH(f32x4_t (&acc)[4][4], bf16_t* sring,
                                       const bf16_t* __restrict__ Ag,
                                       const bf16_t* __restrict__ Bg, int k1,
                                       size_t gA, size_t gB0, size_t gB1,
                                       int aoff, int boff, int tid) {
  if constexpr (STAGE)
    stageH(Ag, Bg, k1, sring + (SC ^ 1) * 12288, gA, gB0, gB1, tid);
  vm_wait<VMN>();
  __builtin_amdgcn_s_barrier();                 // tile t visible block-wide
  const bf16_t* pA = sring + SC * 12288 + aoff;
  const bf16_t* pB = sring + SC * 12288 + 4096 + boff;
  bf16x8_t af[4], bv[4];
  #pragma unroll
  for (int nj = 0; nj < 4; ++nj) bv[nj] = *(const bf16x8_t*)(pB + nj * 512);
  #pragma unroll
  for (int mi = 0; mi < 4; ++mi) af[mi] = *(const bf16x8_t*)(pA + mi * 512);
  __builtin_amdgcn_s_setprio(1);
  #pragma unroll
  for (int mi = 0; mi < 4; ++mi)
    #pragma unroll
    for (int nj = 0; nj < 4; ++nj)
      acc[mi][nj] = __builtin_amdgcn_mfma_f32_16x16x32_bf16(af[mi], bv[nj], acc[mi][nj], 0, 0, 0);
  __builtin_amdgcn_s_setprio(0);
  __builtin_amdgcn_sched_barrier(0);            // reads/MFMA complete above end-bar
  __builtin_amdgcn_s_barrier();                 // slot SC re-stageable
}

template <int K>
__device__ __forceinline__ void kloopH(f32x4_t (&acc)[4][4], bf16_t* sring,
                                       const bf16_t* __restrict__ A, int lda,
                                       const bf16_t* __restrict__ B, int ldb,
                                       int tid, int aoff, int boff) {
  constexpr int T = K / 32;                 // 128 and 12; both even
  static_assert((T & 1) == 0, "T must be even");
  // staging source offsets (16B slot s: row = s>>2, stored chunk = s&3,
  // source chunk = (s&3) ^ ((row>>1)&3) -- rule-21 inverse of the read swizzle)
  const int sa = tid,        ra = sa >> 2, ca = (sa & 3) ^ ((ra >> 1) & 3);
  const int s0 = tid,        r0 = s0 >> 2, c0 = (s0 & 3) ^ ((r0 >> 1) & 3);
  const int s1 = 512 + tid,  r1 = s1 >> 2, c1 = (s1 & 3) ^ ((r1 >> 1) & 3);
  const size_t gA  = (size_t)ra * lda + ca * 8;
  const size_t gB0 = (size_t)r0 * ldb + c0 * 8;
  const size_t gB1 = (size_t)r1 * ldb + c1 * 8;

  stageH(A, B, 0, sring, gA, gB0, gB1, tid);     // prologue: tile 0 -> slot 0
  int t = 0;
  for (; t + 2 < T; t += 2) {               // tiles 0..T-3 (all stage next)
    tbodyH<0, true, 3>(acc, sring, A, B, (t + 1) * 32, gA, gB0, gB1, aoff, boff, tid);
    tbodyH<1, true, 3>(acc, sring, A, B, (t + 2) * 32, gA, gB0, gB1, aoff, boff, tid);
  }
  // final pair: tile T-2 (stages T-1), tile T-1 (drain)
  tbodyH<0, true, 3>(acc, sring, A, B, (T - 1) * 32, gA, gB0, gB1, aoff, boff, tid);
  tbodyH<1, false, 0>(acc, sring, A, B, 0, gA, gB0, gB1, aoff, boff, tid);
}

// 512 threads = 8 waves (2 M-groups x 4 N-groups); per-wave output 64x64.
// LDS: 2-slot ring x 24 KiB (A 8K | B 16K bytes) = 48 KiB -> 2 blocks/CU at <=128 regs.
__global__ __launch_bounds__(512, 4) void gemm_fused256(const bf16_t* __restrict__ xb,
                                                        const bf16_t* __restrict__ WbT,
                                                        const bf16_t* __restrict__ C2b,
                                                        const bf16_t* __restrict__ BbT,
                                                        float* __restrict__ out) {
  __shared__ __align__(16) bf16_t sring[2 * 12288];  // [slot][A 4096 | B 8192] elems
  const int tid = threadIdx.x;
  const int lane = tid & 63;
  const int w = tid >> 6;         // 0..7
  const int wm = w >> 2;          // 0..1  (M half of 128)
  const int wn = w & 3;           // 0..3  (N quarter of 256)
  const int qd = lane >> 4;       // k-chunk
  const int ln = lane & 15;       // row-in-frag
  const int swz8 = ((qd ^ ((ln >> 1) & 3)) << 3);  // swizzled k-chunk, elem units

  // XCD-aware bijective swizzle (512 blocks, 512 % 8 == 0)
  int b = blockIdx.x;
  int sw = (b & 7) * 64 + (b >> 3);
  int bm = sw >> 4, bn = sw & 15;   // bm 0..31, bn 0..15

  const int aoff = (wm * 64 + ln) * 32 + swz8;
  const int boff = (wn * 64 + ln) * 32 + swz8;

  f32x4_t acc[4][4] = {};

  kloopH<D_IN>(acc, sring, xb  + (size_t)bm * 128 * D_IN, D_IN,
                           WbT + (size_t)bn * 256 * D_IN, D_IN, tid, aoff, boff);
  kloopH<KC2>(acc, sring, C2b + (size_t)bm * 128 * KC2,  KC2,
                          BbT + (size_t)bn * 256 * KC2,  KC2,  tid, aoff, boff);

  float* Cb = out + (size_t)(bm * 128 + wm * 64) * O_OUT + bn * 256 + wn * 64;
  #pragma unroll
  for (int mi = 0; mi < 4; ++mi)
    #pragma unroll
    for (int nj = 0; nj < 4; ++nj)
      #pragma unroll
      for (int rg = 0; rg < 4; ++rg)
        Cb[(size_t)(mi * 16 + qd * 4 + rg) * O_OUT + nj * 16 + ln] = acc[mi][nj][rg];
}

// ---------------- launch ----------------
// ws layout (bytes):
//   xb    @ 0         : 33554432  (bf16 [4096,4096])
//   WbT   @ 33554432  : 33554432  (bf16 [4096,4096])
//   PabT  @ 67108864  : 2097152   (bf16 [256,4096])
//   BbT   @ 69206016  : 3145728   (bf16 [4096,384])
//   C2b   @ 72351744  : 3145728   (bf16 [4096,384])
//   gidx  @ 75497472  : 32768
//   gwv   @ 75530240  : 32768
// projP [8][4096][256] fp32 (32 MB) lives in d_out (dead until final GEMM overwrites).
extern "C" void kernel_launch(void* const* d_in, const int* in_sizes, int n_in,
                              void* d_out, int out_size, void* d_ws, size_t ws_size,
                              hipStream_t stream) {
  const float* x       = (const float*)d_in[0];
  const float* base_W  = (const float*)d_in[1];
  const float* routerW = (const float*)d_in[2];
  const float* A       = (const float*)d_in[3];
  const float* B       = (const float*)d_in[4];
  const float* Rm      = (const float*)d_in[5];
  float* out = (float*)d_out;
  char* ws = (char*)d_ws;

  bf16_t* xb   = (bf16_t*)(ws);
  bf16_t* WbT  = (bf16_t*)(ws + 33554432);
  bf16_t* PabT = (bf16_t*)(ws + 67108864);
  bf16_t* BbT  = (bf16_t*)(ws + 69206016);
  bf16_t* C2b  = (bf16_t*)(ws + 72351744);
  int*    gidx = (int*)   (ws + 75497472);
  float*  gwv  = (float*) (ws + 75530240);
  float*  projP = out;  // scratch: fully dead before gemm_fused writes out

  // 1) all independent prep in one saturating launch
  prep_kernel<<<5760, 256, 0, stream>>>(x, base_W, routerW, A, B, Rm,
                                        xb, WbT, BbT, PabT, gidx, gwv);
  // 2) proj split-K GEMM (non-atomic partials into d_out scratch), 2 blocks/CU
  gemm_proj_kernel<<<dim3(32, 2, NKZ), 256, 0, stream>>>(xb, PabT, projP);
  // 3) gating -> C2 (sums NKZ partials)
  gating_kernel<<<4096, 384, 0, stream>>>(projP, gidx, gwv, C2b);
  // 4) fused base+delta GEMM, 128x256 ring-2, 2 blocks/CU cross-block overlap
  gemm_fused256<<<dim3(512), 512, 0, stream>>>(xb, WbT, C2b, BbT, out);
}

// Round 15
// 346.880 us; speedup vs baseline: 1.1025x; 1.1025x over previous
//
#include <hip/hip_runtime.h>
#include <hip/hip_bf16.h>
#include <math.h>

typedef __bf16 bf16_t;
typedef __bf16 bf16x4_t __attribute__((ext_vector_type(4)));
typedef __bf16 bf16x8_t __attribute__((ext_vector_type(8)));
typedef float  f32x4_t  __attribute__((ext_vector_type(4)));

#define N_TOK 4096
#define D_IN  4096
#define O_OUT 4096
#define NEXP  8
#define NHEAD 3
#define RANK  16
#define KC2   384      // E*H*R
#define PCOLS 256      // padded projection cols (152 used)
#define NKZ   8        // proj split-K factor
#define SCALING_F 2.0f

// ---------------- prep building blocks ----------------

// 64x64 transpose tile fp32 -> bf16; 16B bf16x8 stores; LDS reads 2-way aliased (free).
__device__ __forceinline__ void transpose_tile(const float* __restrict__ src,
                                               bf16_t* __restrict__ dst,
                                               int Rr, int Cc, int r0, int c0,
                                               float (*tile)[65]) {
  int q  = threadIdx.x & 15;
  int r4 = threadIdx.x >> 4;
  #pragma unroll
  for (int g = 0; g < 4; ++g) {
    int r = r4 + g * 16;
    float4 v = *(const float4*)(src + (size_t)(r0 + r) * Cc + c0 + q * 4);
    tile[r][q * 4 + 0] = v.x; tile[r][q * 4 + 1] = v.y;
    tile[r][q * 4 + 2] = v.z; tile[r][q * 4 + 3] = v.w;
  }
  __syncthreads();
  int j  = threadIdx.x & 7;   // out col-chunk (8 src rows)
  int cc = threadIdx.x >> 3;  // out row 0..31 (+32)
  #pragma unroll
  for (int h = 0; h < 2; ++h) {
    int c = cc + h * 32;
    bf16x8_t o;
    #pragma unroll
    for (int i = 0; i < 8; ++i) o[i] = (bf16_t)tile[j * 8 + i][c];
    *(bf16x8_t*)(dst + (size_t)(c0 + c) * Rr + r0 + j * 8) = o;
  }
}

// ---------------- ONE prep kernel: all independent pre-GEMM work ----------------
__global__ __launch_bounds__(256) void prep_kernel(const float* __restrict__ x,
                                                   const float* __restrict__ base_W,
                                                   const float* __restrict__ rw,
                                                   const float* __restrict__ A,
                                                   const float* __restrict__ B,
                                                   const float* __restrict__ Rm,
                                                   bf16_t* __restrict__ xb,
                                                   bf16_t* __restrict__ WbT,
                                                   bf16_t* __restrict__ BbT,
                                                   bf16_t* __restrict__ PabT,
                                                   int* __restrict__ gidx,
                                                   float* __restrict__ gwv) {
  __shared__ float tile[64][65];
  int b = blockIdx.x;
  if (b < 4096) {
    transpose_tile(base_W, WbT, 4096, 4096, (b & 63) * 64, (b >> 6) * 64, tile);
  } else if (b < 5120) {
    int lane = threadIdx.x & 63;
    int wv = threadIdx.x >> 6;
    int n = (b - 4096) * 4 + wv;
    const float4* xv = (const float4*)(x + (size_t)n * D_IN);
    bf16x4_t* xo = (bf16x4_t*)(xb + (size_t)n * D_IN);
    float acc[NEXP] = {0, 0, 0, 0, 0, 0, 0, 0};
    for (int d = lane; d < D_IN / 4; d += 64) {
      float4 xx = xv[d];
      bf16x4_t ob = { (bf16_t)xx.x, (bf16_t)xx.y, (bf16_t)xx.z, (bf16_t)xx.w };
      xo[d] = ob;
      #pragma unroll
      for (int e = 0; e < NEXP; ++e) {
        float4 ww = ((const float4*)(rw + (size_t)e * D_IN))[d];
        acc[e] += xx.x * ww.x + xx.y * ww.y + xx.z * ww.z + xx.w * ww.w;
      }
    }
    #pragma unroll
    for (int e = 0; e < NEXP; ++e) {
      float v = acc[e];
      #pragma unroll
      for (int o = 32; o > 0; o >>= 1) v += __shfl_down(v, o);
      acc[e] = v;
    }
    if (lane == 0) {
      int i0 = 0; float l0 = acc[0];
      #pragma unroll
      for (int e = 1; e < NEXP; ++e) if (acc[e] > l0) { l0 = acc[e]; i0 = e; }
      int i1 = -1; float l1 = -3.4e38f;
      #pragma unroll
      for (int e = 0; e < NEXP; ++e) if (e != i0 && acc[e] > l1) { l1 = acc[e]; i1 = e; }
      float w0 = 1.f / (1.f + expf(l1 - l0));
      gidx[2 * n] = i0; gidx[2 * n + 1] = i1;
      gwv[2 * n] = w0;  gwv[2 * n + 1] = 1.f - w0;
    }
  } else if (b < 5504) {
    int t = b - 5120;
    transpose_tile(B, BbT, KC2, 4096, (t % 6) * 64, (t / 6) * 64, tile);
  } else {
    int c = b - 5504;  // 0..255: output row of PabT
    for (int d = threadIdx.x; d < D_IN; d += 256) {
      float v = 0.f;
      if (c < 128) {
        int e = c >> 4, r = c & 15;
        v = A[((size_t)e * D_IN + d) * RANK + r];
      } else if (c < 152) {
        int qq = c - 128; int e = qq / 3, h = qq - 3 * e;
        v = Rm[((size_t)e * D_IN + d) * NHEAD + h];
      }
      PabT[(size_t)c * D_IN + d] = (bf16_t)v;
    }
  }
}

// ---------------- gating: C2[n, e*48+h*16+r], summing NKZ split-K partials ----------------
__global__ void gating_kernel(const float* __restrict__ projP, const int* __restrict__ gidx,
                              const float* __restrict__ gwv, bf16_t* __restrict__ C2b) {
  int n = blockIdx.x;
  int c = threadIdx.x;  // 0..383
  int e = c / 48;
  int h = (c % 48) / 16;
  int r = c & 15;
  int i0 = gidx[2 * n], i1 = gidx[2 * n + 1];
  float g = (e == i0) ? gwv[2 * n] : (e == i1) ? gwv[2 * n + 1] : 0.f;
  float val = 0.f;
  if (g != 0.f) {
    const float* p0 = projP + (size_t)n * PCOLS;
    const size_t S = (size_t)N_TOK * PCOLS;
    float h0 = 0.f, h1 = 0.f, h2 = 0.f, av = 0.f;
    #pragma unroll
    for (int z = 0; z < NKZ; ++z) {
      const float* pz = p0 + (size_t)z * S;
      h0 += pz[128 + e * 3 + 0];
      h1 += pz[128 + e * 3 + 1];
      h2 += pz[128 + e * 3 + 2];
      av += pz[e * 16 + r];
    }
    float mx = fmaxf(h0, fmaxf(h1, h2));
    float e0 = expf(h0 - mx), e1 = expf(h1 - mx), e2 = expf(h2 - mx);
    float hw = (h == 0 ? e0 : h == 1 ? e1 : e2) / (e0 + e1 + e2);
    val = SCALING_F * g * hw * av;
  }
  C2b[(size_t)n * KC2 + c] = (bf16_t)val;
}

// ---------------- m97-style MFMA K-loop core (used by proj GEMM only) ----------------
__device__ __forceinline__ void run_kloop(f32x4_t (&acc)[4][4], bf16_t* sA, bf16_t* sB,
                                          const bf16_t* __restrict__ Ab, int lda,
                                          const bf16_t* __restrict__ Bb, int ldb, int K) {
  const int tid = threadIdx.x;
  const int lane = tid & 63;
  const int w = tid >> 6;
  const int wm = (w >> 1) * 64;
  const int wn = (w & 1) * 64;
  const int qd = lane >> 4;
  const int ln = lane & 15;
  const int sw = ln & 7;

  size_t offA[4], offB[4];
  int lo[4];
  #pragma unroll
  for (int t = 0; t < 4; ++t) {
    int c = tid + t * 256;
    int m = c >> 3, kc = (c & 7) ^ (m & 7);
    offA[t] = (size_t)m * lda + kc * 8;
    offB[t] = (size_t)m * ldb + kc * 8;
    lo[t] = c * 8;
  }
  int rowA[4], rowB[4];
  #pragma unroll
  for (int i = 0; i < 4; ++i) {
    rowA[i] = (wm + i * 16 + ln) * 64;
    rowB[i] = (wn + i * 16 + ln) * 64;
  }

  for (int k0 = 0; k0 < K; k0 += 64) {
    __syncthreads();
    #pragma unroll
    for (int t = 0; t < 4; ++t)
      __builtin_amdgcn_global_load_lds(
          (const __attribute__((address_space(1))) void*)(Ab + k0 + offA[t]),
          (__attribute__((address_space(3))) void*)(sA + lo[t]), 16, 0, 0);
    #pragma unroll
    for (int t = 0; t < 4; ++t)
      __builtin_amdgcn_global_load_lds(
          (const __attribute__((address_space(1))) void*)(Bb + k0 + offB[t]),
          (__attribute__((address_space(3))) void*)(sB + lo[t]), 16, 0, 0);
    __syncthreads();
    #pragma unroll
    for (int s = 0; s < 2; ++s) {
      bf16x8_t af[4], bfr[4];
      int kx = ((s * 4 + qd) ^ sw) * 8;
      #pragma unroll
      for (int i = 0; i < 4; ++i) af[i]  = *(const bf16x8_t*)(sA + rowA[i] + kx);
      #pragma unroll
      for (int i = 0; i < 4; ++i) bfr[i] = *(const bf16x8_t*)(sB + rowB[i] + kx);
      #pragma unroll
      for (int i = 0; i < 4; ++i)
        #pragma unroll
        for (int j = 0; j < 4; ++j)
          acc[i][j] = __builtin_amdgcn_mfma_f32_16x16x32_bf16(af[i], bfr[j], acc[i][j], 0, 0, 0);
    }
  }
}

// proj split-K GEMM: projP[kz][4096,256] = xb @ PabT^T partial (K slice 512), 2 blocks/CU.
__global__ __launch_bounds__(256) void gemm_proj_kernel(const bf16_t* __restrict__ xb,
                                                        const bf16_t* __restrict__ PabT,
                                                        float* __restrict__ projP) {
  __shared__ bf16_t sA[128 * 64];
  __shared__ bf16_t sB[128 * 64];
  int bm = blockIdx.x, bn = blockIdx.y, kz = blockIdx.z;
  f32x4_t acc[4][4] = {};
  run_kloop(acc, sA, sB,
            xb + (size_t)bm * 128 * D_IN + kz * 512, D_IN,
            PabT + (size_t)bn * 128 * D_IN + kz * 512, D_IN, 512);
  const int lane = threadIdx.x & 63, w = threadIdx.x >> 6;
  const int wm = (w >> 1) * 64, wn = (w & 1) * 64, qd = lane >> 4, ln = lane & 15;
  float* Cb = projP + (size_t)kz * N_TOK * PCOLS + (size_t)bm * 128 * PCOLS + bn * 128;
  #pragma unroll
  for (int i = 0; i < 4; ++i)
    #pragma unroll
    for (int j = 0; j < 4; ++j) {
      int col = wn + j * 16 + ln;
      #pragma unroll
      for (int rg = 0; rg < 4; ++rg) {
        int row = wm + i * 16 + qd * 4 + rg;
        Cb[(size_t)row * PCOLS + col] = acc[i][j][rg];
      }
    }
}

// ---------------- fused big GEMM: 256x256, BK=32, ring-4, PHASE-PIPELINED (R6) --------
// EXACT R6/R11/R13 configuration — the measured optimum (fused 123-124 us, MfmaUtil 56%,
// 0 conflicts; total 347.2-348.9, reproduced three times). Complete departure ledger:
// BK=64 null; one-barrier -8us; epilogue repack -4us (+conflicts); 32x32x16 -27us
// (+41M conflicts); early-B -6us; grid-sync merge -57us; 16-wave 1-block -15us
// (block-wide barriers null TLP); 8-wave 2-block small-tile -32us (FETCH 2x, ILP loss).
// Reuse x per-wave ILP at the 256-reg cliff is the binding structure; this is its optimum.
// Schedule per tile t (slot SC=t&3):
//   [carried: bv(t),a0(t) read during t-1 phase b]
//   stage A(t+3);  phase a: 16 MFMA (bv,a0) ; read a1(t) ; stage B(t+3)
//   vmcnt(8) ; mid-bar  (tile t+1 visible)
//   phase b: 16 MFMA (a1,bv) ; read bv(t+1),a0(t+1) from slot (t+1)&3
//   sched_barrier(0) ; end-bar  (slot SC re-stageable)

__device__ __forceinline__ void stage2(const bf16_t* __restrict__ G, int k0,
                                       bf16_t* lbase, size_t g0, size_t g1, int tid) {
  __builtin_amdgcn_global_load_lds(
      (const __attribute__((address_space(1))) void*)(G + g0 + k0),
      (__attribute__((address_space(3))) void*)(lbase + tid * 8), 16, 0, 0);
  __builtin_amdgcn_global_load_lds(
      (const __attribute__((address_space(1))) void*)(G + g1 + k0),
      (__attribute__((address_space(3))) void*)(lbase + 4096 + tid * 8), 16, 0, 0);
}

template <int N>
__device__ __forceinline__ void vm_wait() {
  if constexpr (N == 8)      asm volatile("s_waitcnt vmcnt(8)" ::: "memory");
  else if constexpr (N == 4) asm volatile("s_waitcnt vmcnt(4)" ::: "memory");
  else if constexpr (N == 0) asm volatile("s_waitcnt vmcnt(0)" ::: "memory");
}

// one 16-MFMA quadrant cluster, acc rows MB..MB+3
template <int MB>
__device__ __forceinline__ void mfma16(f32x4_t (&acc)[8][4], const bf16x8_t (&af)[4],
                                       const bf16x8_t (&bv)[4]) {
  __builtin_amdgcn_s_setprio(1);
  #pragma unroll
  for (int mi = 0; mi < 4; ++mi)
    #pragma unroll
    for (int nj = 0; nj < 4; ++nj)
      acc[MB + mi][nj] =
          __builtin_amdgcn_mfma_f32_16x16x32_bf16(af[mi], bv[nj], acc[MB + mi][nj], 0, 0, 0);
  __builtin_amdgcn_s_setprio(0);
}

// pipelined tile body. bv/a0 carried by reference across bodies.
template <int SC, bool STAGE, int VMN, bool NEXTRD>
__device__ __forceinline__ void tbodyP(f32x4_t (&acc)[8][4], bf16_t* sring,
                                       const bf16_t* __restrict__ Ag,
                                       const bf16_t* __restrict__ Bg, int k3,
                                       size_t gA0, size_t gA1, size_t gB0, size_t gB1,
                                       int aoff, int boff, int tid,
                                       bf16x8_t (&bv)[4], bf16x8_t (&a0)[4]) {
  constexpr int SS = (SC + 3) & 3;
  constexpr int SN = (SC + 1) & 3;
  if constexpr (STAGE) stage2(Ag, k3, sring + SS * 16384, gA0, gA1, tid);
  const bf16_t* pA = sring + SC * 16384 + aoff;
  bf16x8_t a1[4];
  mfma16<0>(acc, a0, bv);                       // operands pre-read last phase
  #pragma unroll
  for (int mi = 0; mi < 4; ++mi) a1[mi] = *(const bf16x8_t*)(pA + (4 + mi) * 512);
  if constexpr (STAGE) stage2(Bg, k3, sring + SS * 16384 + 8192, gB0, gB1, tid);
  vm_wait<VMN>();
  __builtin_amdgcn_s_barrier();                 // mid: tile t+1 visible from here
  mfma16<4>(acc, a1, bv);
  if constexpr (NEXTRD) {
    const bf16_t* qA = sring + SN * 16384 + aoff;
    const bf16_t* qB = sring + SN * 16384 + 8192 + boff;
    #pragma unroll
    for (int nj = 0; nj < 4; ++nj) bv[nj] = *(const bf16x8_t*)(qB + nj * 512);
    #pragma unroll
    for (int mi = 0; mi < 4; ++mi) a0[mi] = *(const bf16x8_t*)(qA + mi * 512);
  }
  __builtin_amdgcn_sched_barrier(0);            // pin slot-SC reads above end-bar
  __builtin_amdgcn_s_barrier();                 // end: slot SC re-stageable
}

template <int K>
__device__ __forceinline__ void kloopP(f32x4_t (&acc)[8][4], bf16_t* sring,
                                       const bf16_t* __restrict__ A, int lda,
                                       const bf16_t* __restrict__ B, int ldb,
                                       int tid, int aoff, int boff) {
  constexpr int T = K / 32;                 // 128 and 12; both T%4==0
  static_assert((T & 3) == 0, "T must be multiple of 4");
  const int s0 = tid,       r0 = s0 >> 2, c0 = (s0 & 3) ^ ((r0 >> 1) & 3);
  const int s1 = 512 + tid, r1 = s1 >> 2, c1 = (s1 & 3) ^ ((r1 >> 1) & 3);
  const size_t gA0 = (size_t)r0 * lda + c0 * 8, gA1 = (size_t)r1 * lda + c1 * 8;
  const size_t gB0 = (size_t)r0 * ldb + c0 * 8, gB1 = (size_t)r1 * ldb + c1 * 8;

  #pragma unroll
  for (int t = 0; t < 3; ++t) {             // prologue: tiles 0..2 -> slots 0..2 (12 glds)
    stage2(A, t * 32, sring + t * 16384, gA0, gA1, tid);
    stage2(B, t * 32, sring + t * 16384 + 8192, gB0, gB1, tid);
  }
  asm volatile("s_waitcnt vmcnt(8)" ::: "memory");   // tile 0 landed (oldest 4 of 12)
  __builtin_amdgcn_s_barrier();
  bf16x8_t bv[4], a0[4];
  {
    const bf16_t* qA = sring + aoff;
    const bf16_t* qB = sring + 8192 + boff;
    #pragma unroll
    for (int nj = 0; nj < 4; ++nj) bv[nj] = *(const bf16x8_t*)(qB + nj * 512);
    #pragma unroll
    for (int mi = 0; mi < 4; ++mi) a0[mi] = *(const bf16x8_t*)(qA + mi * 512);
  }
  constexpr int TM = T - 3;                 // TM % 4 == 1 -> leftover is slot 0
  int t = 0;
  for (; t + 3 < TM; t += 4) {
    tbodyP<0,true,8,true>(acc, sring, A, B, (t+3)*32, gA0,gA1,gB0,gB1, aoff,boff,tid, bv,a0);
    tbodyP<1,true,8,true>(acc, sring, A, B, (t+4)*32, gA0,gA1,gB0,gB1, aoff,boff,tid, bv,a0);
    tbodyP<2,true,8,true>(acc, sring, A, B, (t+5)*32, gA0,gA1,gB0,gB1, aoff,boff,tid, bv,a0);
    tbodyP<3,true,8,true>(acc, sring, A, B, (t+6)*32, gA0,gA1,gB0,gB1, aoff,boff,tid, bv,a0);
  }
  // leftover: exactly one body, slot 0, stages tile T-1
  tbodyP<0,true,8,true>(acc, sring, A, B, (t+3)*32, gA0,gA1,gB0,gB1, aoff,boff,tid, bv,a0);
  // tail tiles T-3,T-2,T-1 (slots 1,2,3): no stages; drain 4 -> 0 -> none
  tbodyP<1,false,4,true >(acc, sring, A, B, 0, gA0,gA1,gB0,gB1, aoff,boff,tid, bv,a0);
  tbodyP<2,false,0,true >(acc, sring, A, B, 0, gA0,gA1,gB0,gB1, aoff,boff,tid, bv,a0);
  tbodyP<3,false,-1,false>(acc, sring, A, B, 0, gA0,gA1,gB0,gB1, aoff,boff,tid, bv,a0);
}

// 512 threads = 8 waves (2 M-groups x 4 N-groups); per-wave output 128x64.
// LDS: 4-slot ring x 16 KiB = 128 KiB -> 1 block/CU (2 waves/SIMD; ~256 unified
// regs/wave = the occupancy cliff -- keep per-wave state flat).
__global__ __launch_bounds__(512, 1) void gemm_fused256(const bf16_t* __restrict__ xb,
                                                        const bf16_t* __restrict__ WbT,
                                                        const bf16_t* __restrict__ C2b,
                                                        const bf16_t* __restrict__ BbT,
                                                        float* __restrict__ out) {
  __shared__ __align__(16) bf16_t sring[4 * 16384];  // [slot][A 8192 | B 8192]
  const int tid = threadIdx.x;
  const int lane = tid & 63;
  const int w = tid >> 6;
  const int wm = w >> 2;          // 0..1
  const int wn = w & 3;           // 0..3
  const int qd = lane >> 4;       // k-chunk
  const int ln = lane & 15;       // row-in-frag
  const int swz8 = ((qd ^ ((ln >> 1) & 3)) << 3);  // swizzled k-chunk, elem units

  // XCD-aware bijective swizzle (256 blocks, 256 % 8 == 0)
  int b = blockIdx.x;
  int sw = (b & 7) * 32 + (b >> 3);
  int bm = sw >> 4, bn = sw & 15;

  const int aoff = (wm * 128 + ln) * 32 + swz8;
  const int boff = (wn * 64 + ln) * 32 + swz8;

  f32x4_t acc[8][4] = {};

  kloopP<D_IN>(acc, sring, xb  + (size_t)bm * 256 * D_IN, D_IN,
                           WbT + (size_t)bn * 256 * D_IN, D_IN, tid, aoff, boff);
  kloopP<KC2>(acc, sring, C2b + (size_t)bm * 256 * KC2,  KC2,
                          BbT + (size_t)bn * 256 * KC2,  KC2,  tid, aoff, boff);

  float* Cb = out + (size_t)(bm * 256 + wm * 128) * O_OUT + bn * 256 + wn * 64;
  #pragma unroll
  for (int mi = 0; mi < 8; ++mi)
    #pragma unroll
    for (int nj = 0; nj < 4; ++nj)
      #pragma unroll
      for (int rg = 0; rg < 4; ++rg)
        Cb[(size_t)(mi * 16 + qd * 4 + rg) * O_OUT + nj * 16 + ln] = acc[mi][nj][rg];
}

// ---------------- launch ----------------
// ws layout (bytes):
//   xb    @ 0         : 33554432  (bf16 [4096,4096])
//   WbT   @ 33554432  : 33554432  (bf16 [4096,4096])
//   PabT  @ 67108864  : 2097152   (bf16 [256,4096])
//   BbT   @ 69206016  : 3145728   (bf16 [4096,384])
//   C2b   @ 72351744  : 3145728   (bf16 [4096,384])
//   gidx  @ 75497472  : 32768
//   gwv   @ 75530240  : 32768
// projP [8][4096][256] fp32 (32 MB) lives in d_out (dead until final GEMM overwrites).
extern "C" void kernel_launch(void* const* d_in, const int* in_sizes, int n_in,
                              void* d_out, int out_size, void* d_ws, size_t ws_size,
                              hipStream_t stream) {
  const float* x       = (const float*)d_in[0];
  const float* base_W  = (const float*)d_in[1];
  const float* routerW = (const float*)d_in[2];
  const float* A       = (const float*)d_in[3];
  const float* B       = (const float*)d_in[4];
  const float* Rm      = (const float*)d_in[5];
  float* out = (float*)d_out;
  char* ws = (char*)d_ws;

  bf16_t* xb   = (bf16_t*)(ws);
  bf16_t* WbT  = (bf16_t*)(ws + 33554432);
  bf16_t* PabT = (bf16_t*)(ws + 67108864);
  bf16_t* BbT  = (bf16_t*)(ws + 69206016);
  bf16_t* C2b  = (bf16_t*)(ws + 72351744);
  int*    gidx = (int*)   (ws + 75497472);
  float*  gwv  = (float*) (ws + 75530240);
  float*  projP = out;  // scratch: fully dead before gemm_fused writes out

  // 1) all independent prep in one saturating launch
  prep_kernel<<<5760, 256, 0, stream>>>(x, base_W, routerW, A, B, Rm,
                                        xb, WbT, BbT, PabT, gidx, gwv);
  // 2) proj split-K GEMM (non-atomic partials into d_out scratch), 2 blocks/CU
  gemm_proj_kernel<<<dim3(32, 2, NKZ), 256, 0, stream>>>(xb, PabT, projP);
  // 3) gating -> C2 (sums NKZ partials)
  gating_kernel<<<4096, 384, 0, stream>>>(projP, gidx, gwv, C2b);
  // 4) fused base+delta GEMM, R6 pipelined ring-4, single out write
  gemm_fused256<<<dim3(256), 512, 0, stream>>>(xb, WbT, C2b, BbT, out);
}

// Round 16
// 345.083 us; speedup vs baseline: 1.1083x; 1.0052x over previous
//
#include <hip/hip_runtime.h>
#include <hip/hip_bf16.h>
#include <math.h>

typedef __bf16 bf16_t;
typedef __bf16 bf16x4_t __attribute__((ext_vector_type(4)));
typedef __bf16 bf16x8_t __attribute__((ext_vector_type(8)));
typedef float  f32x4_t  __attribute__((ext_vector_type(4)));

#define N_TOK 4096
#define D_IN  4096
#define O_OUT 4096
#define NEXP  8
#define NHEAD 3
#define RANK  16
#define KC2   384      // E*H*R
#define XK    4480     // stitched K: 4096 (base) + 384 (lora delta)
#define PCOLS 256      // padded projection cols (152 used)
#define NKZ   8        // proj split-K factor
#define SCALING_F 2.0f

// ---------------- prep building blocks ----------------

// 64x64 transpose tile fp32 -> bf16; 16B bf16x8 stores; LDS reads 2-way aliased (free).
// Rr is the DESTINATION row stride (elems).
__device__ __forceinline__ void transpose_tile(const float* __restrict__ src,
                                               bf16_t* __restrict__ dst,
                                               int Rr, int Cc, int r0, int c0,
                                               float (*tile)[65]) {
  int q  = threadIdx.x & 15;
  int r4 = threadIdx.x >> 4;
  #pragma unroll
  for (int g = 0; g < 4; ++g) {
    int r = r4 + g * 16;
    float4 v = *(const float4*)(src + (size_t)(r0 + r) * Cc + c0 + q * 4);
    tile[r][q * 4 + 0] = v.x; tile[r][q * 4 + 1] = v.y;
    tile[r][q * 4 + 2] = v.z; tile[r][q * 4 + 3] = v.w;
  }
  __syncthreads();
  int j  = threadIdx.x & 7;   // out col-chunk (8 src rows)
  int cc = threadIdx.x >> 3;  // out row 0..31 (+32)
  #pragma unroll
  for (int h = 0; h < 2; ++h) {
    int c = cc + h * 32;
    bf16x8_t o;
    #pragma unroll
    for (int i = 0; i < 8; ++i) o[i] = (bf16_t)tile[j * 8 + i][c];
    *(bf16x8_t*)(dst + (size_t)(c0 + c) * Rr + r0 + j * 8) = o;
  }
}

// ---------------- ONE prep kernel: all independent pre-GEMM work ----------------
// Stitched layouts: xb2[4096][XK] (cols 0-4095 = bf16(x); 4096+ filled by gating),
// W2[4096][XK] (cols 0-4095 = base_W^T; 4096+ = Bflat^T).
__global__ __launch_bounds__(256) void prep_kernel(const float* __restrict__ x,
                                                   const float* __restrict__ base_W,
                                                   const float* __restrict__ rw,
                                                   const float* __restrict__ A,
                                                   const float* __restrict__ B,
                                                   const float* __restrict__ Rm,
                                                   bf16_t* __restrict__ xb2,
                                                   bf16_t* __restrict__ W2,
                                                   bf16_t* __restrict__ PabT,
                                                   int* __restrict__ gidx,
                                                   float* __restrict__ gwv) {
  __shared__ float tile[64][65];
  int b = blockIdx.x;
  if (b < 4096) {
    transpose_tile(base_W, W2, XK, 4096, (b & 63) * 64, (b >> 6) * 64, tile);
  } else if (b < 5120) {
    int lane = threadIdx.x & 63;
    int wv = threadIdx.x >> 6;
    int n = (b - 4096) * 4 + wv;
    const float4* xv = (const float4*)(x + (size_t)n * D_IN);
    bf16x4_t* xo = (bf16x4_t*)(xb2 + (size_t)n * XK);   // cols 0..4095 of stitched row
    float acc[NEXP] = {0, 0, 0, 0, 0, 0, 0, 0};
    for (int d = lane; d < D_IN / 4; d += 64) {
      float4 xx = xv[d];
      bf16x4_t ob = { (bf16_t)xx.x, (bf16_t)xx.y, (bf16_t)xx.z, (bf16_t)xx.w };
      xo[d] = ob;
      #pragma unroll
      for (int e = 0; e < NEXP; ++e) {
        float4 ww = ((const float4*)(rw + (size_t)e * D_IN))[d];
        acc[e] += xx.x * ww.x + xx.y * ww.y + xx.z * ww.z + xx.w * ww.w;
      }
    }
    #pragma unroll
    for (int e = 0; e < NEXP; ++e) {
      float v = acc[e];
      #pragma unroll
      for (int o = 32; o > 0; o >>= 1) v += __shfl_down(v, o);
      acc[e] = v;
    }
    if (lane == 0) {
      int i0 = 0; float l0 = acc[0];
      #pragma unroll
      for (int e = 1; e < NEXP; ++e) if (acc[e] > l0) { l0 = acc[e]; i0 = e; }
      int i1 = -1; float l1 = -3.4e38f;
      #pragma unroll
      for (int e = 0; e < NEXP; ++e) if (e != i0 && acc[e] > l1) { l1 = acc[e]; i1 = e; }
      float w0 = 1.f / (1.f + expf(l1 - l0));
      gidx[2 * n] = i0; gidx[2 * n + 1] = i1;
      gwv[2 * n] = w0;  gwv[2 * n + 1] = 1.f - w0;
    }
  } else if (b < 5504) {
    int t = b - 5120;
    // Bflat [384][4096] fp32 -> W2 cols 4096..4479 (row stride XK)
    transpose_tile(B, W2 + 4096, XK, 4096, (t % 6) * 64, (t / 6) * 64, tile);
  } else {
    int c = b - 5504;  // 0..255: output row of PabT
    for (int d = threadIdx.x; d < D_IN; d += 256) {
      float v = 0.f;
      if (c < 128) {
        int e = c >> 4, r = c & 15;
        v = A[((size_t)e * D_IN + d) * RANK + r];
      } else if (c < 152) {
        int qq = c - 128; int e = qq / 3, h = qq - 3 * e;
        v = Rm[((size_t)e * D_IN + d) * NHEAD + h];
      }
      PabT[(size_t)c * D_IN + d] = (bf16_t)v;
    }
  }
}

// ---------------- gating: writes C2 into xb2 cols 4096.., summing NKZ partials ----------
__global__ void gating_kernel(const float* __restrict__ projP, const int* __restrict__ gidx,
                              const float* __restrict__ gwv, bf16_t* __restrict__ xb2) {
  int n = blockIdx.x;
  int c = threadIdx.x;  // 0..383
  int e = c / 48;
  int h = (c % 48) / 16;
  int r = c & 15;
  int i0 = gidx[2 * n], i1 = gidx[2 * n + 1];
  float g = (e == i0) ? gwv[2 * n] : (e == i1) ? gwv[2 * n + 1] : 0.f;
  float val = 0.f;
  if (g != 0.f) {
    const float* p0 = projP + (size_t)n * PCOLS;
    const size_t S = (size_t)N_TOK * PCOLS;
    float h0 = 0.f, h1 = 0.f, h2 = 0.f, av = 0.f;
    #pragma unroll
    for (int z = 0; z < NKZ; ++z) {
      const float* pz = p0 + (size_t)z * S;
      h0 += pz[128 + e * 3 + 0];
      h1 += pz[128 + e * 3 + 1];
      h2 += pz[128 + e * 3 + 2];
      av += pz[e * 16 + r];
    }
    float mx = fmaxf(h0, fmaxf(h1, h2));
    float e0 = expf(h0 - mx), e1 = expf(h1 - mx), e2 = expf(h2 - mx);
    float hw = (h == 0 ? e0 : h == 1 ? e1 : e2) / (e0 + e1 + e2);
    val = SCALING_F * g * hw * av;
  }
  xb2[(size_t)n * XK + 4096 + c] = (bf16_t)val;
}

// ---------------- m97-style MFMA K-loop core (used by proj GEMM only) ----------------
__device__ __forceinline__ void run_kloop(f32x4_t (&acc)[4][4], bf16_t* sA, bf16_t* sB,
                                          const bf16_t* __restrict__ Ab, int lda,
                                          const bf16_t* __restrict__ Bb, int ldb, int K) {
  const int tid = threadIdx.x;
  const int lane = tid & 63;
  const int w = tid >> 6;
  const int wm = (w >> 1) * 64;
  const int wn = (w & 1) * 64;
  const int qd = lane >> 4;
  const int ln = lane & 15;
  const int sw = ln & 7;

  size_t offA[4], offB[4];
  int lo[4];
  #pragma unroll
  for (int t = 0; t < 4; ++t) {
    int c = tid + t * 256;
    int m = c >> 3, kc = (c & 7) ^ (m & 7);
    offA[t] = (size_t)m * lda + kc * 8;
    offB[t] = (size_t)m * ldb + kc * 8;
    lo[t] = c * 8;
  }
  int rowA[4], rowB[4];
  #pragma unroll
  for (int i = 0; i < 4; ++i) {
    rowA[i] = (wm + i * 16 + ln) * 64;
    rowB[i] = (wn + i * 16 + ln) * 64;
  }

  for (int k0 = 0; k0 < K; k0 += 64) {
    __syncthreads();
    #pragma unroll
    for (int t = 0; t < 4; ++t)
      __builtin_amdgcn_global_load_lds(
          (const __attribute__((address_space(1))) void*)(Ab + k0 + offA[t]),
          (__attribute__((address_space(3))) void*)(sA + lo[t]), 16, 0, 0);
    #pragma unroll
    for (int t = 0; t < 4; ++t)
      __builtin_amdgcn_global_load_lds(
          (const __attribute__((address_space(1))) void*)(Bb + k0 + offB[t]),
          (__attribute__((address_space(3))) void*)(sB + lo[t]), 16, 0, 0);
    __syncthreads();
    #pragma unroll
    for (int s = 0; s < 2; ++s) {
      bf16x8_t af[4], bfr[4];
      int kx = ((s * 4 + qd) ^ sw) * 8;
      #pragma unroll
      for (int i = 0; i < 4; ++i) af[i]  = *(const bf16x8_t*)(sA + rowA[i] + kx);
      #pragma unroll
      for (int i = 0; i < 4; ++i) bfr[i] = *(const bf16x8_t*)(sB + rowB[i] + kx);
      #pragma unroll
      for (int i = 0; i < 4; ++i)
        #pragma unroll
        for (int j = 0; j < 4; ++j)
          acc[i][j] = __builtin_amdgcn_mfma_f32_16x16x32_bf16(af[i], bfr[j], acc[i][j], 0, 0, 0);
    }
  }
}

// proj split-K GEMM: projP[kz][4096,256] = xb2[:, :4096] @ PabT^T partial (K slice 512).
__global__ __launch_bounds__(256) void gemm_proj_kernel(const bf16_t* __restrict__ xb2,
                                                        const bf16_t* __restrict__ PabT,
                                                        float* __restrict__ projP) {
  __shared__ bf16_t sA[128 * 64];
  __shared__ bf16_t sB[128 * 64];
  int bm = blockIdx.x, bn = blockIdx.y, kz = blockIdx.z;
  f32x4_t acc[4][4] = {};
  run_kloop(acc, sA, sB,
            xb2 + (size_t)bm * 128 * XK + kz * 512, XK,
            PabT + (size_t)bn * 128 * D_IN + kz * 512, D_IN, 512);
  const int lane = threadIdx.x & 63, w = threadIdx.x >> 6;
  const int wm = (w >> 1) * 64, wn = (w & 1) * 64, qd = lane >> 4, ln = lane & 15;
  float* Cb = projP + (size_t)kz * N_TOK * PCOLS + (size_t)bm * 128 * PCOLS + bn * 128;
  #pragma unroll
  for (int i = 0; i < 4; ++i)
    #pragma unroll
    for (int j = 0; j < 4; ++j) {
      int col = wn + j * 16 + ln;
      #pragma unroll
      for (int rg = 0; rg < 4; ++rg) {
        int row = wm + i * 16 + qd * 4 + rg;
        Cb[(size_t)row * PCOLS + col] = acc[i][j][rg];
      }
    }
}

// ---------------- fused big GEMM: 256x256, BK=32, ring-4, PHASE-PIPELINED (R6) --------
// R6/R11/R13/R15 sync structure byte-identical (the 4x-reproduced optimum: 123-126 us,
// 56% MfmaUtil, 0 conflicts). Round-16 change is ADDRESS-ONLY: the two K-loops
// (K=4096 base + K=384 delta) are stitched into ONE K=4480 loop over xb2/W2
// (row stride XK) -- removes the second pipeline prologue, the inter-loop vmcnt(0)
// drain, and one tail (6 of 152 tile-slots ran degraded before).
// Schedule per tile t (slot SC=t&3):
//   [carried: bv(t),a0(t) read during t-1 phase b]
//   stage A(t+3);  phase a: 16 MFMA (bv,a0) ; read a1(t) ; stage B(t+3)
//   vmcnt(8) ; mid-bar  (tile t+1 visible)
//   phase b: 16 MFMA (a1,bv) ; read bv(t+1),a0(t+1) from slot (t+1)&3
//   sched_barrier(0) ; end-bar  (slot SC re-stageable)

__device__ __forceinline__ void stage2(const bf16_t* __restrict__ G, int k0,
                                       bf16_t* lbase, size_t g0, size_t g1, int tid) {
  __builtin_amdgcn_global_load_lds(
      (const __attribute__((address_space(1))) void*)(G + g0 + k0),
      (__attribute__((address_space(3))) void*)(lbase + tid * 8), 16, 0, 0);
  __builtin_amdgcn_global_load_lds(
      (const __attribute__((address_space(1))) void*)(G + g1 + k0),
      (__attribute__((address_space(3))) void*)(lbase + 4096 + tid * 8), 16, 0, 0);
}

template <int N>
__device__ __forceinline__ void vm_wait() {
  if constexpr (N == 8)      asm volatile("s_waitcnt vmcnt(8)" ::: "memory");
  else if constexpr (N == 4) asm volatile("s_waitcnt vmcnt(4)" ::: "memory");
  else if constexpr (N == 0) asm volatile("s_waitcnt vmcnt(0)" ::: "memory");
}

// one 16-MFMA quadrant cluster, acc rows MB..MB+3
template <int MB>
__device__ __forceinline__ void mfma16(f32x4_t (&acc)[8][4], const bf16x8_t (&af)[4],
                                       const bf16x8_t (&bv)[4]) {
  __builtin_amdgcn_s_setprio(1);
  #pragma unroll
  for (int mi = 0; mi < 4; ++mi)
    #pragma unroll
    for (int nj = 0; nj < 4; ++nj)
      acc[MB + mi][nj] =
          __builtin_amdgcn_mfma_f32_16x16x32_bf16(af[mi], bv[nj], acc[MB + mi][nj], 0, 0, 0);
  __builtin_amdgcn_s_setprio(0);
}

// pipelined tile body. bv/a0 carried by reference across bodies.
template <int SC, bool STAGE, int VMN, bool NEXTRD>
__device__ __forceinline__ void tbodyP(f32x4_t (&acc)[8][4], bf16_t* sring,
                                       const bf16_t* __restrict__ Ag,
                                       const bf16_t* __restrict__ Bg, int k3,
                                       size_t gA0, size_t gA1, size_t gB0, size_t gB1,
                                       int aoff, int boff, int tid,
                                       bf16x8_t (&bv)[4], bf16x8_t (&a0)[4]) {
  constexpr int SS = (SC + 3) & 3;
  constexpr int SN = (SC + 1) & 3;
  if constexpr (STAGE) stage2(Ag, k3, sring + SS * 16384, gA0, gA1, tid);
  const bf16_t* pA = sring + SC * 16384 + aoff;
  bf16x8_t a1[4];
  mfma16<0>(acc, a0, bv);                       // operands pre-read last phase
  #pragma unroll
  for (int mi = 0; mi < 4; ++mi) a1[mi] = *(const bf16x8_t*)(pA + (4 + mi) * 512);
  if constexpr (STAGE) stage2(Bg, k3, sring + SS * 16384 + 8192, gB0, gB1, tid);
  vm_wait<VMN>();
  __builtin_amdgcn_s_barrier();                 // mid: tile t+1 visible from here
  mfma16<4>(acc, a1, bv);
  if constexpr (NEXTRD) {
    const bf16_t* qA = sring + SN * 16384 + aoff;
    const bf16_t* qB = sring + SN * 16384 + 8192 + boff;
    #pragma unroll
    for (int nj = 0; nj < 4; ++nj) bv[nj] = *(const bf16x8_t*)(qB + nj * 512);
    #pragma unroll
    for (int mi = 0; mi < 4; ++mi) a0[mi] = *(const bf16x8_t*)(qA + mi * 512);
  }
  __builtin_amdgcn_sched_barrier(0);            // pin slot-SC reads above end-bar
  __builtin_amdgcn_s_barrier();                 // end: slot SC re-stageable
}

template <int K>
__device__ __forceinline__ void kloopP(f32x4_t (&acc)[8][4], bf16_t* sring,
                                       const bf16_t* __restrict__ A, int lda,
                                       const bf16_t* __restrict__ B, int ldb,
                                       int tid, int aoff, int boff) {
  constexpr int T = K / 32;                 // 140 (stitched); T%4==0
  static_assert((T & 3) == 0, "T must be multiple of 4");
  const int s0 = tid,       r0 = s0 >> 2, c0 = (s0 & 3) ^ ((r0 >> 1) & 3);
  const int s1 = 512 + tid, r1 = s1 >> 2, c1 = (s1 & 3) ^ ((r1 >> 1) & 3);
  const size_t gA0 = (size_t)r0 * lda + c0 * 8, gA1 = (size_t)r1 * lda + c1 * 8;
  const size_t gB0 = (size_t)r0 * ldb + c0 * 8, gB1 = (size_t)r1 * ldb + c1 * 8;

  #pragma unroll
  for (int t = 0; t < 3; ++t) {             // prologue: tiles 0..2 -> slots 0..2 (12 glds)
    stage2(A, t * 32, sring + t * 16384, gA0, gA1, tid);
    stage2(B, t * 32, sring + t * 16384 + 8192, gB0, gB1, tid);
  }
  asm volatile("s_waitcnt vmcnt(8)" ::: "memory");   // tile 0 landed (oldest 4 of 12)
  __builtin_amdgcn_s_barrier();
  bf16x8_t bv[4], a0[4];
  {
    const bf16_t* qA = sring + aoff;
    const bf16_t* qB = sring + 8192 + boff;
    #pragma unroll
    for (int nj = 0; nj < 4; ++nj) bv[nj] = *(const bf16x8_t*)(qB + nj * 512);
    #pragma unroll
    for (int mi = 0; mi < 4; ++mi) a0[mi] = *(const bf16x8_t*)(qA + mi * 512);
  }
  constexpr int TM = T - 3;                 // TM % 4 == 1 -> leftover is slot 0
  int t = 0;
  for (; t + 3 < TM; t += 4) {
    tbodyP<0,true,8,true>(acc, sring, A, B, (t+3)*32, gA0,gA1,gB0,gB1, aoff,boff,tid, bv,a0);
    tbodyP<1,true,8,true>(acc, sring, A, B, (t+4)*32, gA0,gA1,gB0,gB1, aoff,boff,tid, bv,a0);
    tbodyP<2,true,8,true>(acc, sring, A, B, (t+5)*32, gA0,gA1,gB0,gB1, aoff,boff,tid, bv,a0);
    tbodyP<3,true,8,true>(acc, sring, A, B, (t+6)*32, gA0,gA1,gB0,gB1, aoff,boff,tid, bv,a0);
  }
  // leftover: exactly one body, slot 0, stages tile T-1
  tbodyP<0,true,8,true>(acc, sring, A, B, (t+3)*32, gA0,gA1,gB0,gB1, aoff,boff,tid, bv,a0);
  // tail tiles T-3,T-2,T-1 (slots 1,2,3): no stages; drain 4 -> 0 -> none
  tbodyP<1,false,4,true >(acc, sring, A, B, 0, gA0,gA1,gB0,gB1, aoff,boff,tid, bv,a0);
  tbodyP<2,false,0,true >(acc, sring, A, B, 0, gA0,gA1,gB0,gB1, aoff,boff,tid, bv,a0);
  tbodyP<3,false,-1,false>(acc, sring, A, B, 0, gA0,gA1,gB0,gB1, aoff,boff,tid, bv,a0);
}

// 512 threads = 8 waves (2 M-groups x 4 N-groups); per-wave output 128x64.
// LDS: 4-slot ring x 16 KiB = 128 KiB -> 1 block/CU (2 waves/SIMD; ~256 unified
// regs/wave = the occupancy cliff -- keep per-wave state flat).
__global__ __launch_bounds__(512, 1) void gemm_fused256(const bf16_t* __restrict__ xb2,
                                                        const bf16_t* __restrict__ W2,
                                                        float* __restrict__ out) {
  __shared__ __align__(16) bf16_t sring[4 * 16384];  // [slot][A 8192 | B 8192]
  const int tid = threadIdx.x;
  const int lane = tid & 63;
  const int w = tid >> 6;
  const int wm = w >> 2;          // 0..1
  const int wn = w & 3;           // 0..3
  const int qd = lane >> 4;       // k-chunk
  const int ln = lane & 15;       // row-in-frag
  const int swz8 = ((qd ^ ((ln >> 1) & 3)) << 3);  // swizzled k-chunk, elem units

  // XCD-aware bijective swizzle (256 blocks, 256 % 8 == 0)
  int b = blockIdx.x;
  int sw = (b & 7) * 32 + (b >> 3);
  int bm = sw >> 4, bn = sw & 15;

  const int aoff = (wm * 128 + ln) * 32 + swz8;
  const int boff = (wn * 64 + ln) * 32 + swz8;

  f32x4_t acc[8][4] = {};

  kloopP<XK>(acc, sring, xb2 + (size_t)bm * 256 * XK, XK,
                         W2  + (size_t)bn * 256 * XK, XK, tid, aoff, boff);

  float* Cb = out + (size_t)(bm * 256 + wm * 128) * O_OUT + bn * 256 + wn * 64;
  #pragma unroll
  for (int mi = 0; mi < 8; ++mi)
    #pragma unroll
    for (int nj = 0; nj < 4; ++nj)
      #pragma unroll
      for (int rg = 0; rg < 4; ++rg)
        Cb[(size_t)(mi * 16 + qd * 4 + rg) * O_OUT + nj * 16 + ln] = acc[mi][nj][rg];
}

// ---------------- launch ----------------
// ws layout (bytes):
//   xb2   @ 0         : 36700160  (bf16 [4096,4480] = [x_bf16 | C2])
//   W2    @ 36700160  : 36700160  (bf16 [4096,4480] = [base_W^T | Bflat^T])
//   PabT  @ 73400320  : 2097152   (bf16 [256,4096])
//   gidx  @ 75497472  : 32768
//   gwv   @ 75530240  : 32768     (total 75563008 B -- same footprint as before)
// projP [8][4096][256] fp32 (32 MB) lives in d_out (dead until final GEMM overwrites).
extern "C" void kernel_launch(void* const* d_in, const int* in_sizes, int n_in,
                              void* d_out, int out_size, void* d_ws, size_t ws_size,
                              hipStream_t stream) {
  const float* x       = (const float*)d_in[0];
  const float* base_W  = (const float*)d_in[1];
  const float* routerW = (const float*)d_in[2];
  const float* A       = (const float*)d_in[3];
  const float* B       = (const float*)d_in[4];
  const float* Rm      = (const float*)d_in[5];
  float* out = (float*)d_out;
  char* ws = (char*)d_ws;

  bf16_t* xb2  = (bf16_t*)(ws);
  bf16_t* W2   = (bf16_t*)(ws + 36700160);
  bf16_t* PabT = (bf16_t*)(ws + 73400320);
  int*    gidx = (int*)   (ws + 75497472);
  float*  gwv  = (float*) (ws + 75530240);
  float*  projP = out;  // scratch: fully dead before gemm_fused writes out

  // 1) all independent prep in one saturating launch
  prep_kernel<<<5760, 256, 0, stream>>>(x, base_W, routerW, A, B, Rm,
                                        xb2, W2, PabT, gidx, gwv);
  // 2) proj split-K GEMM (non-atomic partials into d_out scratch), 2 blocks/CU
  gemm_proj_kernel<<<dim3(32, 2, NKZ), 256, 0, stream>>>(xb2, PabT, projP);
  // 3) gating -> C2 written into xb2 cols 4096..4479 (sums NKZ partials)
  gating_kernel<<<4096, 384, 0, stream>>>(projP, gidx, gwv, xb2);
  // 4) fused base+delta GEMM: ONE stitched K=4480 pipeline, single out write
  gemm_fused256<<<dim3(256), 512, 0, stream>>>(xb2, W2, out);
}